// Round 1
// baseline (664.942 us; speedup 1.0000x reference)
//
#include <hip/hip_runtime.h>

#define BB 8
#define NN 1024
#define CC 768
#define HH 12
#define DD 64

typedef unsigned short u16;
typedef unsigned int u32;
typedef __attribute__((ext_vector_type(8))) short s16x8;
typedef __attribute__((ext_vector_type(4))) short s16x4;
typedef __attribute__((ext_vector_type(4))) float f32x4;
typedef __attribute__((ext_vector_type(2))) u32 u32x2;
typedef __attribute__((ext_vector_type(4))) u32 u32x4;

__device__ __forceinline__ float bf2f(u16 u) {
  u32 x = ((u32)u) << 16;
  return __builtin_bit_cast(float, x);
}
__device__ __forceinline__ u16 f2bf(float f) {
  u32 x = __builtin_bit_cast(u32, f);
  x += 0x7fffu + ((x >> 16) & 1u);
  return (u16)(x >> 16);
}
// hardware exp2 / log2 (v_exp_f32 / v_log_f32)
__device__ __forceinline__ float hw_exp2(float x) { return __builtin_amdgcn_exp2f(x); }
__device__ __forceinline__ float hw_log2(float x) { return __builtin_amdgcn_logf(x); }
// 16B LDS read as 2x8B (rows are 8B- but not 16B-aligned at conflict-free pitches)
__device__ __forceinline__ s16x8 lds_read8(const u16* p) {
  u32x2 a = *(const u32x2*)p;
  u32x2 b = *(const u32x2*)(p + 4);
  u32x4 m = {a.x, a.y, b.x, b.y};
  return __builtin_bit_cast(s16x8, m);
}
// pack f32 v into u32: low16 = bf16-trunc(v), high16 = bf16-trunc(v - hi).
// 4 VALU (and, sub, lshr, and_or) vs ~8 for RNE f2bf pair; err <= 2^-16|v|.
__device__ __forceinline__ u32 packhl(float v) {
  u32 xv = __builtin_bit_cast(u32, v);
  float lo = v - __builtin_bit_cast(float, xv & 0xFFFF0000u);
  return (xv >> 16) | (__builtin_bit_cast(u32, lo) & 0xFFFF0000u);
}
// async global->LDS 16B/lane. LDS dest is wave-uniform base + lane*16.
__device__ __forceinline__ void gload_lds16(const u16* g, u16* l) {
  __builtin_amdgcn_global_load_lds(
      (const __attribute__((address_space(1))) u32*)g,
      (__attribute__((address_space(3))) u32*)l, 16, 0, 0);
}

// ---------------------------------------------------------------------------
// x fp32 -> bf16
// ---------------------------------------------------------------------------
__global__ __launch_bounds__(256) void convx_kernel(const float* __restrict__ in,
                                                    u16* __restrict__ out) {
  size_t i = ((size_t)blockIdx.x * 256 + threadIdx.x) * 8;
  f32x4 a = *(const f32x4*)(in + i);
  f32x4 b = *(const f32x4*)(in + i + 4);
  s16x8 r;
#pragma unroll
  for (int j = 0; j < 4; j++) { r[j] = (short)f2bf(a[j]); r[4 + j] = (short)f2bf(b[j]); }
  *(s16x8*)(out + i) = r;
}

// ---------------------------------------------------------------------------
// fp32 [R][C] -> bf16 [C][R]
// ---------------------------------------------------------------------------
__global__ __launch_bounds__(256) void transpose_kernel(const float* __restrict__ in,
                                                        u16* __restrict__ out,
                                                        int R, int C) {
  __shared__ float t[32][33];
  const int cl = threadIdx.x & 31, rq = threadIdx.x >> 5;
#pragma unroll
  for (int rr = 0; rr < 4; rr++) {
    int rl = rq * 4 + rr;
    t[rl][cl] = in[(size_t)(blockIdx.y * 32 + rl) * C + blockIdx.x * 32 + cl];
  }
  __syncthreads();
#pragma unroll
  for (int rr = 0; rr < 4; rr++) {
    int oc = rq * 4 + rr;
    out[(size_t)(blockIdx.x * 32 + oc) * R + blockIdx.y * 32 + cl] = f2bf(t[cl][oc]);
  }
}

// ---------------------------------------------------------------------------
// QKV GEMM: 128x128 tile, BK=32, global_load_lds staging
//  -> q,k [b][h][n][d] (q x0.125), v^T [b][h][d][n]
// ---------------------------------------------------------------------------
__global__ __launch_bounds__(256) void qkv_gemm(
    const u16* __restrict__ A, const u16* __restrict__ Bt, const float* __restrict__ bias,
    u16* __restrict__ qo, u16* __restrict__ ko, u16* __restrict__ vo) {
  __shared__ __align__(16) u16 As[128 * 32];
  __shared__ __align__(16) u16 Bs[128 * 32];
  const int tid = threadIdx.x;
  const int w = tid >> 6, lane = tid & 63, l15 = lane & 15, l4 = lane >> 4;
  const int wm = w & 1, wn = w >> 1;
  const int m0 = blockIdx.x * 128, n0 = blockIdx.y * 128;
  const int grow = lane >> 2, gcol = (lane & 3) * 8;  // staging row-in-chunk / u16 col

  f32x4 acc[4][4];
#pragma unroll
  for (int a = 0; a < 4; a++)
#pragma unroll
    for (int bb = 0; bb < 4; bb++) acc[a][bb] = (f32x4){0.f, 0.f, 0.f, 0.f};

  for (int k0 = 0; k0 < CC; k0 += 32) {
    __syncthreads();  // prev-iter frag reads complete before LDS overwrite
    const u16* ga = A + (size_t)(m0 + w * 32 + grow) * CC + k0 + gcol;
    const u16* gb = Bt + (size_t)(n0 + w * 32 + grow) * CC + k0 + gcol;
    gload_lds16(ga, &As[w * 1024]);
    gload_lds16(ga + (size_t)16 * CC, &As[w * 1024 + 512]);
    gload_lds16(gb, &Bs[w * 1024]);
    gload_lds16(gb + (size_t)16 * CC, &Bs[w * 1024 + 512]);
    __syncthreads();  // drains vmcnt -> tiles resident
    s16x8 af[4], bf[4];
#pragma unroll
    for (int a = 0; a < 4; a++) af[a] = *(const s16x8*)&As[(wm * 64 + a * 16 + l15) * 32 + l4 * 8];
#pragma unroll
    for (int bb = 0; bb < 4; bb++) bf[bb] = *(const s16x8*)&Bs[(wn * 64 + bb * 16 + l15) * 32 + l4 * 8];
#pragma unroll
    for (int a = 0; a < 4; a++)
#pragma unroll
      for (int bb = 0; bb < 4; bb++)
        acc[a][bb] = __builtin_amdgcn_mfma_f32_16x16x32_bf16(af[a], bf[bb], acc[a][bb], 0, 0, 0);
  }

  const int b = (m0 >> 10);
#pragma unroll
  for (int bb = 0; bb < 4; bb++) {
    int col = n0 + wn * 64 + bb * 16 + l15;
    int s = col / CC;
    int rem = col - s * CC;
    int h = rem >> 6, d = rem & 63;
    float bv = bias[col];
#pragma unroll
    for (int a = 0; a < 4; a++) {
      int row0 = m0 + wm * 64 + a * 16 + l4 * 4;
      int nt0 = row0 & (NN - 1);
      if (s == 2) {
        s16x4 pk;
#pragma unroll
        for (int r = 0; r < 4; r++) pk[r] = (short)f2bf(acc[a][bb][r] + bv);
        *(s16x4*)(vo + (((size_t)((b * HH + h) * DD + d)) << 10) + nt0) = pk;
      } else if (s == 0) {
#pragma unroll
        for (int r = 0; r < 4; r++)
          qo[(((size_t)((b * HH + h) * NN + nt0 + r)) << 6) + d] = f2bf((acc[a][bb][r] + bv) * 0.125f);
      } else {
#pragma unroll
        for (int r = 0; r < 4; r++)
          ko[(((size_t)((b * HH + h) * NN + nt0 + r)) << 6) + d] = f2bf(acc[a][bb][r] + bv);
      }
    }
  }
}

// ---------------------------------------------------------------------------
// Proj GEMM -> fp32 out (global_load_lds staging)
// ---------------------------------------------------------------------------
__global__ __launch_bounds__(256) void proj_gemm(
    const u16* __restrict__ A, const u16* __restrict__ Bt, const float* __restrict__ bias,
    float* __restrict__ out) {
  __shared__ __align__(16) u16 As[128 * 32];
  __shared__ __align__(16) u16 Bs[128 * 32];
  const int tid = threadIdx.x;
  const int w = tid >> 6, lane = tid & 63, l15 = lane & 15, l4 = lane >> 4;
  const int wm = w & 1, wn = w >> 1;
  const int m0 = blockIdx.x * 128, n0 = blockIdx.y * 128;
  const int grow = lane >> 2, gcol = (lane & 3) * 8;

  f32x4 acc[4][4];
#pragma unroll
  for (int a = 0; a < 4; a++)
#pragma unroll
    for (int bb = 0; bb < 4; bb++) acc[a][bb] = (f32x4){0.f, 0.f, 0.f, 0.f};

  for (int k0 = 0; k0 < CC; k0 += 32) {
    __syncthreads();
    const u16* ga = A + (size_t)(m0 + w * 32 + grow) * CC + k0 + gcol;
    const u16* gb = Bt + (size_t)(n0 + w * 32 + grow) * CC + k0 + gcol;
    gload_lds16(ga, &As[w * 1024]);
    gload_lds16(ga + (size_t)16 * CC, &As[w * 1024 + 512]);
    gload_lds16(gb, &Bs[w * 1024]);
    gload_lds16(gb + (size_t)16 * CC, &Bs[w * 1024 + 512]);
    __syncthreads();
    s16x8 af[4], bf[4];
#pragma unroll
    for (int a = 0; a < 4; a++) af[a] = *(const s16x8*)&As[(wm * 64 + a * 16 + l15) * 32 + l4 * 8];
#pragma unroll
    for (int bb = 0; bb < 4; bb++) bf[bb] = *(const s16x8*)&Bs[(wn * 64 + bb * 16 + l15) * 32 + l4 * 8];
#pragma unroll
    for (int a = 0; a < 4; a++)
#pragma unroll
      for (int bb = 0; bb < 4; bb++)
        acc[a][bb] = __builtin_amdgcn_mfma_f32_16x16x32_bf16(af[a], bf[bb], acc[a][bb], 0, 0, 0);
  }

#pragma unroll
  for (int bb = 0; bb < 4; bb++) {
    int col = n0 + wn * 64 + bb * 16 + l15;
    float bv = bias[col];
#pragma unroll
    for (int a = 0; a < 4; a++) {
      int row0 = m0 + wm * 64 + a * 16 + l4 * 4;
#pragma unroll
      for (int r = 0; r < 4; r++)
        out[(size_t)(row0 + r) * CC + col] = acc[a][bb][r] + bv;
    }
  }
}

// ---------------------------------------------------------------------------
// Talking-heads attention, all-MFMA, exp2-folded, conflict-free pitches.
// Block 512 thr per (b, 16 q-rows); grid (8,64) -> b pinned per XCD.
//
// pass1 (1 barrier per m-tile via double-buffered pitch-20 S):
//   QK -> Sp[mt&1]; sync; T=wl'.S+bl' (1 MFMA); l += exp2(T)
// between: ll2 = log2(l); Tinit = bl' - ll2  (folds 1/l into C-init)
// pass2 (PV pipelined one m-tile behind):
//   A: issue V loads for PV(mt-1); QK -> Sb hi/lo (pitch 28)
//   sync1
//   B: bU reads (Ut[prev]); tt: T via 2 MFMA, P=exp2 packed hi/lo in regs,
//      U via 2 MFMA + bw -> Ut[cur] (pitch 36, dbuf);
//      PV(mt-1): pure-reg MFMA cluster under s_setprio(1)
//   sync2
//
// LDS map (bytes): [0,28736) pass-2 Sb (pitch 28) -- also pass-1 bufA region
//   [0,20544) p1 bufA | [20544,41088) p1 bufB (pitch 20; overlaps Ut0 start)
//   [28736,42560) Ut0 | [42560,56384) Ut1 | [48192,56384) lpart (dead by p2)
//   [56384,57472) ll2.  Stale pass-1 bf16 under pass-2 pads is finite and
//   hits zeroed A-fragment k-slots -> contributes exact 0.
// ---------------------------------------------------------------------------
#define SB2_BYTES 28736            // pass-2 S region (512*28*2 + 64 tail)
#define UT_OFF    SB2_BYTES
#define UT_ELE    6912             // 192*36 u16 per Ut buffer
#define SB1_U16   10272            // 512*20 + 32 tail (u16) per pass-1 buffer
#define LPART_OFF 48192
#define LL2_OFF   56384
#define SM_TOTAL  (LL2_OFF + 1088)

__global__ __launch_bounds__(512, 4) void attn_kernel(
    const u16* __restrict__ qg, const u16* __restrict__ kg, const u16* __restrict__ vtg,
    const float* __restrict__ wlg, const float* __restrict__ blg,
    const float* __restrict__ wwg, const float* __restrict__ bwg,
    u16* __restrict__ aout) {
  __shared__ __align__(16) char smem[SM_TOTAL];
  u16* Sb = (u16*)smem;                    // pass-2 S, pitch 28
  u16* Sb1 = (u16*)smem;                   // pass-1 dbuf base, pitch 20
  u16* Ut0 = (u16*)(smem + UT_OFF);
  float* lpart = (float*)(smem + LPART_OFF);
  float* ll2 = (float*)(smem + LL2_OFF);   // [16][17]

  const int b = blockIdx.x, i0 = blockIdx.y * 16;
  const int tid = threadIdx.x;
  const int w = tid >> 6, lane = tid & 63, l15 = lane & 15, l4 = lane >> 4;
  const float RLN2 = 1.44269504088896340736f;

  // zero pass-1 dbuf region [0,41088): pads must never be NaN bit patterns
  for (int j = tid; j < 10272; j += 512) ((u32*)smem)[j] = 0;
  __syncthreads();  // zero visible before any S writes

  // ---- weight A-fragments: lane holds A[row=g=l15][k=l4*8+j] ----
  s16x8 wlS, wlA1, wlA2, wwA1, wwA2;
#pragma unroll
  for (int j = 0; j < 8; j++) {
    int k = l4 * 8 + j;
    float v1 = (k < 12 && l15 < 12) ? wlg[k * 12 + l15] * RLN2 : 0.f;
    wlS[j] = (short)f2bf(v1);
    int h = k >> 1, pt = k & 1;
    float v2 = (h < 12 && l15 < 12) ? wlg[h * 12 + l15] * RLN2 : 0.f;
    u16 h2 = f2bf(v2); u16 lo2 = f2bf(v2 - bf2f(h2));
    wlA1[j] = (short)h2; wlA2[j] = (short)(pt ? 0 : lo2);
    float v3 = (h < 12 && l15 < 12) ? wwg[h * 12 + l15] : 0.f;
    u16 h3 = f2bf(v3); u16 lo3 = f2bf(v3 - bf2f(h3));
    wwA1[j] = (short)h3; wwA2[j] = (short)(pt ? 0 : lo3);
  }
  int gr[4]; float blv[4], bwv[4];
#pragma unroll
  for (int r = 0; r < 4; r++) {
    gr[r] = l4 * 4 + r;
    blv[r] = (gr[r] < 12) ? blg[gr[r]] * RLN2 : 0.f;
    bwv[r] = (gr[r] < 12) ? bwg[gr[r]] : 0.f;
  }

  // ---- QK jobs (12h x 2mb over 8 waves) + Q B-frags ----
  int jh[3], jmb[3];
  s16x8 qf[3][2];
#pragma unroll
  for (int jt = 0; jt < 3; jt++) {
    int j = w * 3 + jt;
    jh[jt] = j % 12; jmb[jt] = j / 12;
    const u16* qp = qg + (((size_t)((b * HH + jh[jt]) * NN + i0 + l15)) << 6) + l4 * 8;
    qf[jt][0] = *(const s16x8*)qp;
    qf[jt][1] = *(const s16x8*)(qp + 32);
  }

  // ================= pass 1: sum-exp (single-bf16 S, dbuf, 1 barrier/mt) ====
  float la[4] = {0.f, 0.f, 0.f, 0.f};
  for (int mt = 0; mt < 32; mt++) {
    const int m0 = mt * 32;
    u16* Sp = Sb1 + (mt & 1) * SB1_U16;
#pragma unroll
    for (int jt = 0; jt < 3; jt++) {
      f32x4 c = (f32x4){0.f, 0.f, 0.f, 0.f};
      const u16* kp = kg + (((size_t)((b * HH + jh[jt]) * NN + m0 + jmb[jt] * 16 + l15)) << 6) + l4 * 8;
      c = __builtin_amdgcn_mfma_f32_16x16x32_bf16(*(const s16x8*)kp, qf[jt][0], c, 0, 0, 0);
      c = __builtin_amdgcn_mfma_f32_16x16x32_bf16(*(const s16x8*)(kp + 32), qf[jt][1], c, 0, 0, 0);
      int cb = (jmb[jt] * 16 + l4 * 4) * 16 + l15;
#pragma unroll
      for (int r = 0; r < 4; r++)
        Sp[(size_t)(cb + r * 16) * 20 + jh[jt]] = f2bf(c[r]);
    }
    __syncthreads();
#pragma unroll
    for (int tt = 0; tt < 4; tt++) {
      int t = w * 4 + tt;
      s16x8 bS = lds_read8(Sp + (size_t)(t * 16 + l15) * 20 + l4 * 8);
      f32x4 T = (f32x4){blv[0], blv[1], blv[2], blv[3]};
      T = __builtin_amdgcn_mfma_f32_16x16x32_bf16(wlS, bS, T, 0, 0, 0);
#pragma unroll
      for (int r = 0; r < 4; r++) la[r] += hw_exp2(T[r]);
    }
    // next iteration's QK writes the other buffer: no trailing barrier needed
  }

  // ---- reduce l across waves; Tinit = bl' - log2(l) ----
#pragma unroll
  for (int r = 0; r < 4; r++) lpart[w * 256 + gr[r] * 16 + l15] = la[r];
  __syncthreads();
  if (tid < 256) {
    float s = 0.f;
#pragma unroll
    for (int w2 = 0; w2 < 8; w2++) s += lpart[w2 * 256 + tid];
    ll2[(tid >> 4) * 17 + (tid & 15)] = hw_log2(s);
  }
  __syncthreads();
  float Tinit[4];
#pragma unroll
  for (int r = 0; r < 4; r++) Tinit[r] = blv[r] - ll2[gr[r] * 17 + l15];

  // ================= pass 2: full (hi/lo S, in-reg P, pipelined PV) =========
  const int db = w >> 1, pvh = (w & 1) * 6;
  f32x4 O[6];
#pragma unroll
  for (int jp = 0; jp < 6; jp++) O[jp] = (f32x4){0.f, 0.f, 0.f, 0.f};
  s16x8 aV[6], bU[6];

  for (int mt = 0; mt < 32; mt++) {
    const int m0 = mt * 32;
    u16* Utw = Ut0 + (mt & 1) * UT_ELE;
    const u16* Utr = Ut0 + ((mt & 1) ^ 1) * UT_ELE;

    // issue V loads for PV(mt-1) early: drained free at sync1
    if (mt > 0) {
#pragma unroll
      for (int jp = 0; jp < 6; jp++) {
        const int h = pvh + jp;
        aV[jp] = *(const s16x8*)(vtg + (((size_t)((b * HH + h) * DD + db * 16 + l15)) << 10) + (m0 - 32) + l4 * 8);
      }
    }
#pragma unroll
    for (int jt = 0; jt < 3; jt++) {
      f32x4 c = (f32x4){0.f, 0.f, 0.f, 0.f};
      const u16* kp = kg + (((size_t)((b * HH + jh[jt]) * NN + m0 + jmb[jt] * 16 + l15)) << 6) + l4 * 8;
      c = __builtin_amdgcn_mfma_f32_16x16x32_bf16(*(const s16x8*)kp, qf[jt][0], c, 0, 0, 0);
      c = __builtin_amdgcn_mfma_f32_16x16x32_bf16(*(const s16x8*)(kp + 32), qf[jt][1], c, 0, 0, 0);
      int cb = (jmb[jt] * 16 + l4 * 4) * 16 + l15;
#pragma unroll
      for (int r = 0; r < 4; r++)
        *(u32*)(Sb + (size_t)(cb + r * 16) * 28 + 2 * jh[jt]) = packhl(c[r]);
    }
    __syncthreads();  // sync1
    // Ut[prev] reads for PV(mt-1): ~400cy of tt work covers the latency
    if (mt > 0) {
#pragma unroll
      for (int jp = 0; jp < 6; jp++)
        bU[jp] = lds_read8(Utr + (size_t)((pvh + jp) * 16 + l15) * 36 + l4 * 8);
    }
#pragma unroll
    for (int tt = 0; tt < 4; tt++) {
      int t = w * 4 + tt;
      s16x8 bS = lds_read8(Sb + (size_t)(t * 16 + l15) * 28 + l4 * 8);
      f32x4 T = (f32x4){Tinit[0], Tinit[1], Tinit[2], Tinit[3]};
      T = __builtin_amdgcn_mfma_f32_16x16x32_bf16(wlA1, bS, T, 0, 0, 0);
      T = __builtin_amdgcn_mfma_f32_16x16x32_bf16(wlA2, bS, T, 0, 0, 0);
      u32x4 pk;
#pragma unroll
      for (int r = 0; r < 4; r++) pk[r] = packhl(hw_exp2(T[r]));  // normalized via Tinit
      s16x8 bP = __builtin_bit_cast(s16x8, pk);  // == ww-mix B-frag in-lane
      f32x4 U = (f32x4){bwv[0], bwv[1], bwv[2], bwv[3]};
      U = __builtin_amdgcn_mfma_f32_16x16x32_bf16(wwA1, bP, U, 0, 0, 0);
      U = __builtin_amdgcn_mfma_f32_16x16x32_bf16(wwA2, bP, U, 0, 0, 0);
#pragma unroll
      for (int r = 0; r < 4; r++)
        if (gr[r] < 12) Utw[(size_t)(gr[r] * 16 + l15) * 36 + t] = f2bf(U[r]);
    }
    // PV(mt-1): pure-register MFMA cluster
    if (mt > 0) {
      __builtin_amdgcn_s_setprio(1);
#pragma unroll
      for (int jp = 0; jp < 6; jp++)
        O[jp] = __builtin_amdgcn_mfma_f32_16x16x32_bf16(aV[jp], bU[jp], O[jp], 0, 0, 0);
      __builtin_amdgcn_s_setprio(0);
    }
    __syncthreads();  // sync2: protects Sb overwrite by next QK
  }
  // epilogue PV for mt=31 (Ut buf 1; written before final sync2 -> safe)
  {
    const u16* Utr = Ut0 + UT_ELE;
#pragma unroll
    for (int jp = 0; jp < 6; jp++) {
      const int h = pvh + jp;
      s16x8 aVe = *(const s16x8*)(vtg + (((size_t)((b * HH + h) * DD + db * 16 + l15)) << 10) + 31 * 32 + l4 * 8);
      s16x8 bUe = lds_read8(Utr + (size_t)(h * 16 + l15) * 36 + l4 * 8);
      O[jp] = __builtin_amdgcn_mfma_f32_16x16x32_bf16(aVe, bUe, O[jp], 0, 0, 0);
    }
  }

  // epilogue: O^T frag rows=d, col=i -> ao[b][n][h*64+d]
#pragma unroll
  for (int jp = 0; jp < 6; jp++) {
    const int h = pvh + jp;
    const int d0 = db * 16 + l4 * 4;
    s16x4 pk4;
#pragma unroll
    for (int r = 0; r < 4; r++) pk4[r] = (short)f2bf(O[jp][r]);
    *(s16x4*)(aout + ((size_t)(b * NN) + i0 + l15) * CC + h * DD + d0) = pk4;
  }
}

extern "C" void kernel_launch(void* const* d_in, const int* in_sizes, int n_in,
                              void* d_out, int out_size, void* d_ws, size_t ws_size,
                              hipStream_t stream) {
  const float* x      = (const float*)d_in[0];
  const float* w_qkv  = (const float*)d_in[1];
  const float* b_qkv  = (const float*)d_in[2];
  const float* w_l    = (const float*)d_in[3];
  const float* b_l    = (const float*)d_in[4];
  const float* w_w    = (const float*)d_in[5];
  const float* b_w    = (const float*)d_in[6];
  const float* w_proj = (const float*)d_in[7];
  const float* b_proj = (const float*)d_in[8];

  const size_t per = (size_t)BB * HH * NN * DD;  // 6,291,456
  u16* xb  = (u16*)d_ws;
  u16* wqt = xb + per;
  u16* wpt = wqt + (size_t)3 * CC * CC;
  u16* q   = wpt + (size_t)CC * CC;
  u16* k   = q + per;
  u16* vt  = k + per;
  u16* ao  = vt + per;

  convx_kernel<<<3072, 256, 0, stream>>>(x, xb);
  transpose_kernel<<<dim3(3 * CC / 32, CC / 32), 256, 0, stream>>>(w_qkv, wqt, CC, 3 * CC);
  transpose_kernel<<<dim3(CC / 32, CC / 32), 256, 0, stream>>>(w_proj, wpt, CC, CC);
  qkv_gemm<<<dim3(64, 18), 256, 0, stream>>>(xb, wqt, b_qkv, q, k, vt);
  attn_kernel<<<dim3(BB, NN / 16), 512, 0, stream>>>(q, k, vt, w_l, b_l, w_w, b_w, ao);
  proj_gemm<<<dim3(64, 6), 256, 0, stream>>>(ao, wpt, b_proj, (float*)d_out);
}

// Round 2
// 471.055 us; speedup vs baseline: 1.4116x; 1.4116x over previous
//
#include <hip/hip_runtime.h>

#define BB 8
#define NN 1024
#define CC 768
#define HH 12
#define DD 64

typedef unsigned short u16;
typedef unsigned int u32;
typedef __attribute__((ext_vector_type(8))) short s16x8;
typedef __attribute__((ext_vector_type(4))) short s16x4;
typedef __attribute__((ext_vector_type(4))) float f32x4;
typedef __attribute__((ext_vector_type(2))) u32 u32x2;
typedef __attribute__((ext_vector_type(4))) u32 u32x4;

__device__ __forceinline__ float bf2f(u16 u) {
  u32 x = ((u32)u) << 16;
  return __builtin_bit_cast(float, x);
}
__device__ __forceinline__ u16 f2bf(float f) {
  u32 x = __builtin_bit_cast(u32, f);
  x += 0x7fffu + ((x >> 16) & 1u);
  return (u16)(x >> 16);
}
// hardware exp2 / log2 (v_exp_f32 / v_log_f32)
__device__ __forceinline__ float hw_exp2(float x) { return __builtin_amdgcn_exp2f(x); }
__device__ __forceinline__ float hw_log2(float x) { return __builtin_amdgcn_logf(x); }
// 16B LDS read as 2x8B (rows are 8B- but not 16B-aligned at conflict-free pitches)
__device__ __forceinline__ s16x8 lds_read8(const u16* p) {
  u32x2 a = *(const u32x2*)p;
  u32x2 b = *(const u32x2*)(p + 4);
  u32x4 m = {a.x, a.y, b.x, b.y};
  return __builtin_bit_cast(s16x8, m);
}
// pack f32 v into u32: low16 = bf16-trunc(v), high16 = bf16-trunc(v - hi).
// 4 VALU (and, sub, lshr, and_or) vs ~8 for RNE f2bf pair; err <= 2^-16|v|.
__device__ __forceinline__ u32 packhl(float v) {
  u32 xv = __builtin_bit_cast(u32, v);
  float lo = v - __builtin_bit_cast(float, xv & 0xFFFF0000u);
  return (xv >> 16) | (__builtin_bit_cast(u32, lo) & 0xFFFF0000u);
}
// async global->LDS 16B/lane. LDS dest is wave-uniform base + lane*16.
__device__ __forceinline__ void gload_lds16(const u16* g, u16* l) {
  __builtin_amdgcn_global_load_lds(
      (const __attribute__((address_space(1))) u32*)g,
      (__attribute__((address_space(3))) u32*)l, 16, 0, 0);
}

// ---------------------------------------------------------------------------
// x fp32 -> bf16
// ---------------------------------------------------------------------------
__global__ __launch_bounds__(256) void convx_kernel(const float* __restrict__ in,
                                                    u16* __restrict__ out) {
  size_t i = ((size_t)blockIdx.x * 256 + threadIdx.x) * 8;
  f32x4 a = *(const f32x4*)(in + i);
  f32x4 b = *(const f32x4*)(in + i + 4);
  s16x8 r;
#pragma unroll
  for (int j = 0; j < 4; j++) { r[j] = (short)f2bf(a[j]); r[4 + j] = (short)f2bf(b[j]); }
  *(s16x8*)(out + i) = r;
}

// ---------------------------------------------------------------------------
// fp32 [R][C] -> bf16 [C][R]
// ---------------------------------------------------------------------------
__global__ __launch_bounds__(256) void transpose_kernel(const float* __restrict__ in,
                                                        u16* __restrict__ out,
                                                        int R, int C) {
  __shared__ float t[32][33];
  const int cl = threadIdx.x & 31, rq = threadIdx.x >> 5;
#pragma unroll
  for (int rr = 0; rr < 4; rr++) {
    int rl = rq * 4 + rr;
    t[rl][cl] = in[(size_t)(blockIdx.y * 32 + rl) * C + blockIdx.x * 32 + cl];
  }
  __syncthreads();
#pragma unroll
  for (int rr = 0; rr < 4; rr++) {
    int oc = rq * 4 + rr;
    out[(size_t)(blockIdx.x * 32 + oc) * R + blockIdx.y * 32 + cl] = f2bf(t[cl][oc]);
  }
}

// ---------------------------------------------------------------------------
// QKV GEMM: 128x128 tile, BK=32, global_load_lds staging
//  -> q,k [b][h][n][d] (q x0.125), v^T [b][h][d][n]
// ---------------------------------------------------------------------------
__global__ __launch_bounds__(256) void qkv_gemm(
    const u16* __restrict__ A, const u16* __restrict__ Bt, const float* __restrict__ bias,
    u16* __restrict__ qo, u16* __restrict__ ko, u16* __restrict__ vo) {
  __shared__ __align__(16) u16 As[128 * 32];
  __shared__ __align__(16) u16 Bs[128 * 32];
  const int tid = threadIdx.x;
  const int w = tid >> 6, lane = tid & 63, l15 = lane & 15, l4 = lane >> 4;
  const int wm = w & 1, wn = w >> 1;
  const int m0 = blockIdx.x * 128, n0 = blockIdx.y * 128;
  const int grow = lane >> 2, gcol = (lane & 3) * 8;  // staging row-in-chunk / u16 col

  f32x4 acc[4][4];
#pragma unroll
  for (int a = 0; a < 4; a++)
#pragma unroll
    for (int bb = 0; bb < 4; bb++) acc[a][bb] = (f32x4){0.f, 0.f, 0.f, 0.f};

  for (int k0 = 0; k0 < CC; k0 += 32) {
    __syncthreads();  // prev-iter frag reads complete before LDS overwrite
    const u16* ga = A + (size_t)(m0 + w * 32 + grow) * CC + k0 + gcol;
    const u16* gb = Bt + (size_t)(n0 + w * 32 + grow) * CC + k0 + gcol;
    gload_lds16(ga, &As[w * 1024]);
    gload_lds16(ga + (size_t)16 * CC, &As[w * 1024 + 512]);
    gload_lds16(gb, &Bs[w * 1024]);
    gload_lds16(gb + (size_t)16 * CC, &Bs[w * 1024 + 512]);
    __syncthreads();  // drains vmcnt -> tiles resident
    s16x8 af[4], bf[4];
#pragma unroll
    for (int a = 0; a < 4; a++) af[a] = *(const s16x8*)&As[(wm * 64 + a * 16 + l15) * 32 + l4 * 8];
#pragma unroll
    for (int bb = 0; bb < 4; bb++) bf[bb] = *(const s16x8*)&Bs[(wn * 64 + bb * 16 + l15) * 32 + l4 * 8];
#pragma unroll
    for (int a = 0; a < 4; a++)
#pragma unroll
      for (int bb = 0; bb < 4; bb++)
        acc[a][bb] = __builtin_amdgcn_mfma_f32_16x16x32_bf16(af[a], bf[bb], acc[a][bb], 0, 0, 0);
  }

  const int b = (m0 >> 10);
#pragma unroll
  for (int bb = 0; bb < 4; bb++) {
    int col = n0 + wn * 64 + bb * 16 + l15;
    int s = col / CC;
    int rem = col - s * CC;
    int h = rem >> 6, d = rem & 63;
    float bv = bias[col];
#pragma unroll
    for (int a = 0; a < 4; a++) {
      int row0 = m0 + wm * 64 + a * 16 + l4 * 4;
      int nt0 = row0 & (NN - 1);
      if (s == 2) {
        s16x4 pk;
#pragma unroll
        for (int r = 0; r < 4; r++) pk[r] = (short)f2bf(acc[a][bb][r] + bv);
        *(s16x4*)(vo + (((size_t)((b * HH + h) * DD + d)) << 10) + nt0) = pk;
      } else if (s == 0) {
#pragma unroll
        for (int r = 0; r < 4; r++)
          qo[(((size_t)((b * HH + h) * NN + nt0 + r)) << 6) + d] = f2bf((acc[a][bb][r] + bv) * 0.125f);
      } else {
#pragma unroll
        for (int r = 0; r < 4; r++)
          ko[(((size_t)((b * HH + h) * NN + nt0 + r)) << 6) + d] = f2bf(acc[a][bb][r] + bv);
      }
    }
  }
}

// ---------------------------------------------------------------------------
// Proj GEMM -> fp32 out (global_load_lds staging)
// ---------------------------------------------------------------------------
__global__ __launch_bounds__(256) void proj_gemm(
    const u16* __restrict__ A, const u16* __restrict__ Bt, const float* __restrict__ bias,
    float* __restrict__ out) {
  __shared__ __align__(16) u16 As[128 * 32];
  __shared__ __align__(16) u16 Bs[128 * 32];
  const int tid = threadIdx.x;
  const int w = tid >> 6, lane = tid & 63, l15 = lane & 15, l4 = lane >> 4;
  const int wm = w & 1, wn = w >> 1;
  const int m0 = blockIdx.x * 128, n0 = blockIdx.y * 128;
  const int grow = lane >> 2, gcol = (lane & 3) * 8;

  f32x4 acc[4][4];
#pragma unroll
  for (int a = 0; a < 4; a++)
#pragma unroll
    for (int bb = 0; bb < 4; bb++) acc[a][bb] = (f32x4){0.f, 0.f, 0.f, 0.f};

  for (int k0 = 0; k0 < CC; k0 += 32) {
    __syncthreads();
    const u16* ga = A + (size_t)(m0 + w * 32 + grow) * CC + k0 + gcol;
    const u16* gb = Bt + (size_t)(n0 + w * 32 + grow) * CC + k0 + gcol;
    gload_lds16(ga, &As[w * 1024]);
    gload_lds16(ga + (size_t)16 * CC, &As[w * 1024 + 512]);
    gload_lds16(gb, &Bs[w * 1024]);
    gload_lds16(gb + (size_t)16 * CC, &Bs[w * 1024 + 512]);
    __syncthreads();
    s16x8 af[4], bf[4];
#pragma unroll
    for (int a = 0; a < 4; a++) af[a] = *(const s16x8*)&As[(wm * 64 + a * 16 + l15) * 32 + l4 * 8];
#pragma unroll
    for (int bb = 0; bb < 4; bb++) bf[bb] = *(const s16x8*)&Bs[(wn * 64 + bb * 16 + l15) * 32 + l4 * 8];
#pragma unroll
    for (int a = 0; a < 4; a++)
#pragma unroll
      for (int bb = 0; bb < 4; bb++)
        acc[a][bb] = __builtin_amdgcn_mfma_f32_16x16x32_bf16(af[a], bf[bb], acc[a][bb], 0, 0, 0);
  }

#pragma unroll
  for (int bb = 0; bb < 4; bb++) {
    int col = n0 + wn * 64 + bb * 16 + l15;
    float bv = bias[col];
#pragma unroll
    for (int a = 0; a < 4; a++) {
      int row0 = m0 + wm * 64 + a * 16 + l4 * 4;
#pragma unroll
      for (int r = 0; r < 4; r++)
        out[(size_t)(row0 + r) * CC + col] = acc[a][bb][r] + bv;
    }
  }
}

// ---------------------------------------------------------------------------
// Talking-heads attention, all-MFMA, exp2-folded, conflict-free pitches.
// Block 512 thr per (b, 16 q-rows); grid (8,64) -> b pinned per XCD.
//
// pass1 (1 barrier per m-tile via double-buffered pitch-20 S):
//   QK -> Sp[mt&1]; sync; T=wl'.S+bl' (1 MFMA); l += exp2(T)
// between: ll2 = log2(l); Tinit = bl' - ll2  (folds 1/l into C-init)
// pass2 (2 barriers per m-tile; SHORT live ranges -- no cross-phase regs.
//   Round-1 lesson: holding aV[6]+bU[6] across tt blew the 128-unified-reg
//   cap of __launch_bounds__(512,4) -> spill -> L2 thrash -> 28x HBM fetch):
//   QK -> Sb hi/lo (pitch 28, packhl); sync1
//   tt: T via 2 MFMA, P=exp2 packed hi/lo in regs == ww B-frag,
//       U via 2 MFMA + bw -> Ut (pitch 36, dbuf); sync2
//   PV: per jp {V global load, Ut LDS read, MFMA} under s_setprio(1)
//
// LDS map (bytes): [0,28736) pass-2 Sb (pitch 28) -- also pass-1 bufA region
//   [0,20544) p1 bufA | [20544,41088) p1 bufB (pitch 20; overlaps Ut0 start)
//   [28736,42560) Ut0 | [42560,56384) Ut1 | [48192,56384) lpart (dead by p2)
//   [56384,57472) ll2.  Stale pass-1 bf16 under pass-2 pads is finite and
//   hits zeroed A-fragment k-slots -> contributes exact 0.
// ---------------------------------------------------------------------------
#define SB2_BYTES 28736            // pass-2 S region (512*28*2 + 64 tail)
#define UT_OFF    SB2_BYTES
#define UT_ELE    6912             // 192*36 u16 per Ut buffer
#define SB1_U16   10272            // 512*20 + 32 tail (u16) per pass-1 buffer
#define LPART_OFF 48192
#define LL2_OFF   56384
#define SM_TOTAL  (LL2_OFF + 1088)

__global__ __launch_bounds__(512, 4) void attn_kernel(
    const u16* __restrict__ qg, const u16* __restrict__ kg, const u16* __restrict__ vtg,
    const float* __restrict__ wlg, const float* __restrict__ blg,
    const float* __restrict__ wwg, const float* __restrict__ bwg,
    u16* __restrict__ aout) {
  __shared__ __align__(16) char smem[SM_TOTAL];
  u16* Sb = (u16*)smem;                    // pass-2 S, pitch 28
  u16* Sb1 = (u16*)smem;                   // pass-1 dbuf base, pitch 20
  u16* Ut0 = (u16*)(smem + UT_OFF);
  float* lpart = (float*)(smem + LPART_OFF);
  float* ll2 = (float*)(smem + LL2_OFF);   // [16][17]

  const int b = blockIdx.x, i0 = blockIdx.y * 16;
  const int tid = threadIdx.x;
  const int w = tid >> 6, lane = tid & 63, l15 = lane & 15, l4 = lane >> 4;
  const float RLN2 = 1.44269504088896340736f;

  // zero pass-1 dbuf region [0,41088): pads must never be NaN bit patterns
  for (int j = tid; j < 10272; j += 512) ((u32*)smem)[j] = 0;
  __syncthreads();  // zero visible before any S writes

  // ---- weight A-fragments: lane holds A[row=g=l15][k=l4*8+j] ----
  s16x8 wlS, wlA1, wlA2, wwA1, wwA2;
#pragma unroll
  for (int j = 0; j < 8; j++) {
    int k = l4 * 8 + j;
    float v1 = (k < 12 && l15 < 12) ? wlg[k * 12 + l15] * RLN2 : 0.f;
    wlS[j] = (short)f2bf(v1);
    int h = k >> 1, pt = k & 1;
    float v2 = (h < 12 && l15 < 12) ? wlg[h * 12 + l15] * RLN2 : 0.f;
    u16 h2 = f2bf(v2); u16 lo2 = f2bf(v2 - bf2f(h2));
    wlA1[j] = (short)h2; wlA2[j] = (short)(pt ? 0 : lo2);
    float v3 = (h < 12 && l15 < 12) ? wwg[h * 12 + l15] : 0.f;
    u16 h3 = f2bf(v3); u16 lo3 = f2bf(v3 - bf2f(h3));
    wwA1[j] = (short)h3; wwA2[j] = (short)(pt ? 0 : lo3);
  }
  int gr[4]; float blv[4], bwv[4];
#pragma unroll
  for (int r = 0; r < 4; r++) {
    gr[r] = l4 * 4 + r;
    blv[r] = (gr[r] < 12) ? blg[gr[r]] * RLN2 : 0.f;
    bwv[r] = (gr[r] < 12) ? bwg[gr[r]] : 0.f;
  }

  // ---- QK jobs (12h x 2mb over 8 waves) + Q B-frags ----
  int jh[3], jmb[3];
  s16x8 qf[3][2];
#pragma unroll
  for (int jt = 0; jt < 3; jt++) {
    int j = w * 3 + jt;
    jh[jt] = j % 12; jmb[jt] = j / 12;
    const u16* qp = qg + (((size_t)((b * HH + jh[jt]) * NN + i0 + l15)) << 6) + l4 * 8;
    qf[jt][0] = *(const s16x8*)qp;
    qf[jt][1] = *(const s16x8*)(qp + 32);
  }

  // ================= pass 1: sum-exp (single-bf16 S, dbuf, 1 barrier/mt) ====
  float la[4] = {0.f, 0.f, 0.f, 0.f};
  for (int mt = 0; mt < 32; mt++) {
    const int m0 = mt * 32;
    u16* Sp = Sb1 + (mt & 1) * SB1_U16;
#pragma unroll
    for (int jt = 0; jt < 3; jt++) {
      f32x4 c = (f32x4){0.f, 0.f, 0.f, 0.f};
      const u16* kp = kg + (((size_t)((b * HH + jh[jt]) * NN + m0 + jmb[jt] * 16 + l15)) << 6) + l4 * 8;
      c = __builtin_amdgcn_mfma_f32_16x16x32_bf16(*(const s16x8*)kp, qf[jt][0], c, 0, 0, 0);
      c = __builtin_amdgcn_mfma_f32_16x16x32_bf16(*(const s16x8*)(kp + 32), qf[jt][1], c, 0, 0, 0);
      int cb = (jmb[jt] * 16 + l4 * 4) * 16 + l15;
#pragma unroll
      for (int r = 0; r < 4; r++)
        Sp[(size_t)(cb + r * 16) * 20 + jh[jt]] = f2bf(c[r]);
    }
    __syncthreads();
#pragma unroll
    for (int tt = 0; tt < 4; tt++) {
      int t = w * 4 + tt;
      s16x8 bS = lds_read8(Sp + (size_t)(t * 16 + l15) * 20 + l4 * 8);
      f32x4 T = (f32x4){blv[0], blv[1], blv[2], blv[3]};
      T = __builtin_amdgcn_mfma_f32_16x16x32_bf16(wlS, bS, T, 0, 0, 0);
#pragma unroll
      for (int r = 0; r < 4; r++) la[r] += hw_exp2(T[r]);
    }
    // next iteration's QK writes the other buffer: no trailing barrier needed
  }

  // ---- reduce l across waves; Tinit = bl' - log2(l) ----
#pragma unroll
  for (int r = 0; r < 4; r++) lpart[w * 256 + gr[r] * 16 + l15] = la[r];
  __syncthreads();
  if (tid < 256) {
    float s = 0.f;
#pragma unroll
    for (int w2 = 0; w2 < 8; w2++) s += lpart[w2 * 256 + tid];
    ll2[(tid >> 4) * 17 + (tid & 15)] = hw_log2(s);
  }
  __syncthreads();
  float Tinit[4];
#pragma unroll
  for (int r = 0; r < 4; r++) Tinit[r] = blv[r] - ll2[gr[r] * 17 + l15];

  // ================= pass 2: full (hi/lo S, in-reg P, PV) =================
  const int db = w >> 1, pvh = (w & 1) * 6;
  f32x4 O[6];
#pragma unroll
  for (int jp = 0; jp < 6; jp++) O[jp] = (f32x4){0.f, 0.f, 0.f, 0.f};

  for (int mt = 0; mt < 32; mt++) {
    const int m0 = mt * 32;
    u16* Utb = Ut0 + (mt & 1) * UT_ELE;
#pragma unroll
    for (int jt = 0; jt < 3; jt++) {
      f32x4 c = (f32x4){0.f, 0.f, 0.f, 0.f};
      const u16* kp = kg + (((size_t)((b * HH + jh[jt]) * NN + m0 + jmb[jt] * 16 + l15)) << 6) + l4 * 8;
      c = __builtin_amdgcn_mfma_f32_16x16x32_bf16(*(const s16x8*)kp, qf[jt][0], c, 0, 0, 0);
      c = __builtin_amdgcn_mfma_f32_16x16x32_bf16(*(const s16x8*)(kp + 32), qf[jt][1], c, 0, 0, 0);
      int cb = (jmb[jt] * 16 + l4 * 4) * 16 + l15;
#pragma unroll
      for (int r = 0; r < 4; r++)
        *(u32*)(Sb + (size_t)(cb + r * 16) * 28 + 2 * jh[jt]) = packhl(c[r]);
    }
    __syncthreads();  // sync1: S resident
#pragma unroll
    for (int tt = 0; tt < 4; tt++) {
      int t = w * 4 + tt;
      s16x8 bS = lds_read8(Sb + (size_t)(t * 16 + l15) * 28 + l4 * 8);
      f32x4 T = (f32x4){Tinit[0], Tinit[1], Tinit[2], Tinit[3]};
      T = __builtin_amdgcn_mfma_f32_16x16x32_bf16(wlA1, bS, T, 0, 0, 0);
      T = __builtin_amdgcn_mfma_f32_16x16x32_bf16(wlA2, bS, T, 0, 0, 0);
      u32x4 pk;
#pragma unroll
      for (int r = 0; r < 4; r++) pk[r] = packhl(hw_exp2(T[r]));  // normalized via Tinit
      s16x8 bP = __builtin_bit_cast(s16x8, pk);  // == ww-mix B-frag in-lane
      f32x4 U = (f32x4){bwv[0], bwv[1], bwv[2], bwv[3]};
      U = __builtin_amdgcn_mfma_f32_16x16x32_bf16(wwA1, bP, U, 0, 0, 0);
      U = __builtin_amdgcn_mfma_f32_16x16x32_bf16(wwA2, bP, U, 0, 0, 0);
#pragma unroll
      for (int r = 0; r < 4; r++)
        if (gr[r] < 12) Utb[(size_t)(gr[r] * 16 + l15) * 36 + t] = f2bf(U[r]);
    }
    __syncthreads();  // sync2: Ut resident
    __builtin_amdgcn_s_setprio(1);
#pragma unroll
    for (int jp = 0; jp < 6; jp++) {
      const int h = pvh + jp;
      s16x8 aV = *(const s16x8*)(vtg + (((size_t)((b * HH + h) * DD + db * 16 + l15)) << 10) + m0 + l4 * 8);
      s16x8 bU = lds_read8(Utb + (size_t)(h * 16 + l15) * 36 + l4 * 8);
      O[jp] = __builtin_amdgcn_mfma_f32_16x16x32_bf16(aV, bU, O[jp], 0, 0, 0);
    }
    __builtin_amdgcn_s_setprio(0);
  }

  // epilogue: O^T frag rows=d, col=i -> ao[b][n][h*64+d]
#pragma unroll
  for (int jp = 0; jp < 6; jp++) {
    const int h = pvh + jp;
    const int d0 = db * 16 + l4 * 4;
    s16x4 pk4;
#pragma unroll
    for (int r = 0; r < 4; r++) pk4[r] = (short)f2bf(O[jp][r]);
    *(s16x4*)(aout + ((size_t)(b * NN) + i0 + l15) * CC + h * DD + d0) = pk4;
  }
}

extern "C" void kernel_launch(void* const* d_in, const int* in_sizes, int n_in,
                              void* d_out, int out_size, void* d_ws, size_t ws_size,
                              hipStream_t stream) {
  const float* x      = (const float*)d_in[0];
  const float* w_qkv  = (const float*)d_in[1];
  const float* b_qkv  = (const float*)d_in[2];
  const float* w_l    = (const float*)d_in[3];
  const float* b_l    = (const float*)d_in[4];
  const float* w_w    = (const float*)d_in[5];
  const float* b_w    = (const float*)d_in[6];
  const float* w_proj = (const float*)d_in[7];
  const float* b_proj = (const float*)d_in[8];

  const size_t per = (size_t)BB * HH * NN * DD;  // 6,291,456
  u16* xb  = (u16*)d_ws;
  u16* wqt = xb + per;
  u16* wpt = wqt + (size_t)3 * CC * CC;
  u16* q   = wpt + (size_t)CC * CC;
  u16* k   = q + per;
  u16* vt  = k + per;
  u16* ao  = vt + per;

  convx_kernel<<<3072, 256, 0, stream>>>(x, xb);
  transpose_kernel<<<dim3(3 * CC / 32, CC / 32), 256, 0, stream>>>(w_qkv, wqt, CC, 3 * CC);
  transpose_kernel<<<dim3(CC / 32, CC / 32), 256, 0, stream>>>(w_proj, wpt, CC, CC);
  qkv_gemm<<<dim3(64, 18), 256, 0, stream>>>(xb, wqt, b_qkv, q, k, vt);
  attn_kernel<<<dim3(BB, NN / 16), 512, 0, stream>>>(q, k, vt, w_l, b_l, w_w, b_w, ao);
  proj_gemm<<<dim3(64, 6), 256, 0, stream>>>(ao, wpt, b_proj, (float*)d_out);
}

// Round 4
// 446.390 us; speedup vs baseline: 1.4896x; 1.0553x over previous
//
#include <hip/hip_runtime.h>

#define BB 8
#define NN 1024
#define CC 768
#define HH 12
#define DD 64

typedef unsigned short u16;
typedef unsigned int u32;
typedef __attribute__((ext_vector_type(8))) short s16x8;
typedef __attribute__((ext_vector_type(4))) short s16x4;
typedef __attribute__((ext_vector_type(4))) float f32x4;
typedef __attribute__((ext_vector_type(2))) u32 u32x2;
typedef __attribute__((ext_vector_type(4))) u32 u32x4;

__device__ __forceinline__ float bf2f(u16 u) {
  u32 x = ((u32)u) << 16;
  return __builtin_bit_cast(float, x);
}
__device__ __forceinline__ u16 f2bf(float f) {
  u32 x = __builtin_bit_cast(u32, f);
  x += 0x7fffu + ((x >> 16) & 1u);
  return (u16)(x >> 16);
}
// hardware exp2 / log2 (v_exp_f32 / v_log_f32)
__device__ __forceinline__ float hw_exp2(float x) { return __builtin_amdgcn_exp2f(x); }
__device__ __forceinline__ float hw_log2(float x) { return __builtin_amdgcn_logf(x); }
// 16B LDS read as 2x8B (rows are 8B- but not 16B-aligned at conflict-free pitches)
__device__ __forceinline__ s16x8 lds_read8(const u16* p) {
  u32x2 a = *(const u32x2*)p;
  u32x2 b = *(const u32x2*)(p + 4);
  u32x4 m = {a.x, a.y, b.x, b.y};
  return __builtin_bit_cast(s16x8, m);
}
// pack f32 v into u32: low16 = bf16-trunc(v), high16 = bf16-trunc(v - hi).
// 4 VALU (and, sub, lshr, and_or) vs ~8 for RNE f2bf pair; err <= 2^-16|v|.
// Verified round-2: VALUBusy -5 points, absmax unchanged.
__device__ __forceinline__ u32 packhl(float v) {
  u32 xv = __builtin_bit_cast(u32, v);
  float lo = v - __builtin_bit_cast(float, xv & 0xFFFF0000u);
  return (xv >> 16) | (__builtin_bit_cast(u32, lo) & 0xFFFF0000u);
}
// async global->LDS 16B/lane. LDS dest is wave-uniform base + lane*16.
__device__ __forceinline__ void gload_lds16(const u16* g, u16* l) {
  __builtin_amdgcn_global_load_lds(
      (const __attribute__((address_space(1))) u32*)g,
      (__attribute__((address_space(3))) u32*)l, 16, 0, 0);
}

// ---------------------------------------------------------------------------
// x fp32 -> bf16
// ---------------------------------------------------------------------------
__global__ __launch_bounds__(256) void convx_kernel(const float* __restrict__ in,
                                                    u16* __restrict__ out) {
  size_t i = ((size_t)blockIdx.x * 256 + threadIdx.x) * 8;
  f32x4 a = *(const f32x4*)(in + i);
  f32x4 b = *(const f32x4*)(in + i + 4);
  s16x8 r;
#pragma unroll
  for (int j = 0; j < 4; j++) { r[j] = (short)f2bf(a[j]); r[4 + j] = (short)f2bf(b[j]); }
  *(s16x8*)(out + i) = r;
}

// ---------------------------------------------------------------------------
// fp32 [R][C] -> bf16 [C][R]
// ---------------------------------------------------------------------------
__global__ __launch_bounds__(256) void transpose_kernel(const float* __restrict__ in,
                                                        u16* __restrict__ out,
                                                        int R, int C) {
  __shared__ float t[32][33];
  const int cl = threadIdx.x & 31, rq = threadIdx.x >> 5;
#pragma unroll
  for (int rr = 0; rr < 4; rr++) {
    int rl = rq * 4 + rr;
    t[rl][cl] = in[(size_t)(blockIdx.y * 32 + rl) * C + blockIdx.x * 32 + cl];
  }
  __syncthreads();
#pragma unroll
  for (int rr = 0; rr < 4; rr++) {
    int oc = rq * 4 + rr;
    out[(size_t)(blockIdx.x * 32 + oc) * R + blockIdx.y * 32 + cl] = f2bf(t[cl][oc]);
  }
}

// ---------------------------------------------------------------------------
// QKV GEMM: 128x128 tile, BK=32, global_load_lds staging (round-2 win, keep)
//  -> q,k [b][h][n][d] (q x0.125), v^T [b][h][d][n]
// ---------------------------------------------------------------------------
__global__ __launch_bounds__(256) void qkv_gemm(
    const u16* __restrict__ A, const u16* __restrict__ Bt, const float* __restrict__ bias,
    u16* __restrict__ qo, u16* __restrict__ ko, u16* __restrict__ vo) {
  __shared__ __align__(16) u16 As[128 * 32];
  __shared__ __align__(16) u16 Bs[128 * 32];
  const int tid = threadIdx.x;
  const int w = tid >> 6, lane = tid & 63, l15 = lane & 15, l4 = lane >> 4;
  const int wm = w & 1, wn = w >> 1;
  const int m0 = blockIdx.x * 128, n0 = blockIdx.y * 128;
  const int grow = lane >> 2, gcol = (lane & 3) * 8;  // staging row-in-chunk / u16 col

  f32x4 acc[4][4];
#pragma unroll
  for (int a = 0; a < 4; a++)
#pragma unroll
    for (int bb = 0; bb < 4; bb++) acc[a][bb] = (f32x4){0.f, 0.f, 0.f, 0.f};

  for (int k0 = 0; k0 < CC; k0 += 32) {
    __syncthreads();  // prev-iter frag reads complete before LDS overwrite
    const u16* ga = A + (size_t)(m0 + w * 32 + grow) * CC + k0 + gcol;
    const u16* gb = Bt + (size_t)(n0 + w * 32 + grow) * CC + k0 + gcol;
    gload_lds16(ga, &As[w * 1024]);
    gload_lds16(ga + (size_t)16 * CC, &As[w * 1024 + 512]);
    gload_lds16(gb, &Bs[w * 1024]);
    gload_lds16(gb + (size_t)16 * CC, &Bs[w * 1024 + 512]);
    __syncthreads();  // drains vmcnt -> tiles resident
    s16x8 af[4], bf[4];
#pragma unroll
    for (int a = 0; a < 4; a++) af[a] = *(const s16x8*)&As[(wm * 64 + a * 16 + l15) * 32 + l4 * 8];
#pragma unroll
    for (int bb = 0; bb < 4; bb++) bf[bb] = *(const s16x8*)&Bs[(wn * 64 + bb * 16 + l15) * 32 + l4 * 8];
#pragma unroll
    for (int a = 0; a < 4; a++)
#pragma unroll
      for (int bb = 0; bb < 4; bb++)
        acc[a][bb] = __builtin_amdgcn_mfma_f32_16x16x32_bf16(af[a], bf[bb], acc[a][bb], 0, 0, 0);
  }

  const int b = (m0 >> 10);
#pragma unroll
  for (int bb = 0; bb < 4; bb++) {
    int col = n0 + wn * 64 + bb * 16 + l15;
    int s = col / CC;
    int rem = col - s * CC;
    int h = rem >> 6, d = rem & 63;
    float bv = bias[col];
#pragma unroll
    for (int a = 0; a < 4; a++) {
      int row0 = m0 + wm * 64 + a * 16 + l4 * 4;
      int nt0 = row0 & (NN - 1);
      if (s == 2) {
        s16x4 pk;
#pragma unroll
        for (int r = 0; r < 4; r++) pk[r] = (short)f2bf(acc[a][bb][r] + bv);
        *(s16x4*)(vo + (((size_t)((b * HH + h) * DD + d)) << 10) + nt0) = pk;
      } else if (s == 0) {
#pragma unroll
        for (int r = 0; r < 4; r++)
          qo[(((size_t)((b * HH + h) * NN + nt0 + r)) << 6) + d] = f2bf((acc[a][bb][r] + bv) * 0.125f);
      } else {
#pragma unroll
        for (int r = 0; r < 4; r++)
          ko[(((size_t)((b * HH + h) * NN + nt0 + r)) << 6) + d] = f2bf(acc[a][bb][r] + bv);
      }
    }
  }
}

// ---------------------------------------------------------------------------
// Proj GEMM -> fp32 out (global_load_lds staging)
// ---------------------------------------------------------------------------
__global__ __launch_bounds__(256) void proj_gemm(
    const u16* __restrict__ A, const u16* __restrict__ Bt, const float* __restrict__ bias,
    float* __restrict__ out) {
  __shared__ __align__(16) u16 As[128 * 32];
  __shared__ __align__(16) u16 Bs[128 * 32];
  const int tid = threadIdx.x;
  const int w = tid >> 6, lane = tid & 63, l15 = lane & 15, l4 = lane >> 4;
  const int wm = w & 1, wn = w >> 1;
  const int m0 = blockIdx.x * 128, n0 = blockIdx.y * 128;
  const int grow = lane >> 2, gcol = (lane & 3) * 8;

  f32x4 acc[4][4];
#pragma unroll
  for (int a = 0; a < 4; a++)
#pragma unroll
    for (int bb = 0; bb < 4; bb++) acc[a][bb] = (f32x4){0.f, 0.f, 0.f, 0.f};

  for (int k0 = 0; k0 < CC; k0 += 32) {
    __syncthreads();
    const u16* ga = A + (size_t)(m0 + w * 32 + grow) * CC + k0 + gcol;
    const u16* gb = Bt + (size_t)(n0 + w * 32 + grow) * CC + k0 + gcol;
    gload_lds16(ga, &As[w * 1024]);
    gload_lds16(ga + (size_t)16 * CC, &As[w * 1024 + 512]);
    gload_lds16(gb, &Bs[w * 1024]);
    gload_lds16(gb + (size_t)16 * CC, &Bs[w * 1024 + 512]);
    __syncthreads();
    s16x8 af[4], bf[4];
#pragma unroll
    for (int a = 0; a < 4; a++) af[a] = *(const s16x8*)&As[(wm * 64 + a * 16 + l15) * 32 + l4 * 8];
#pragma unroll
    for (int bb = 0; bb < 4; bb++) bf[bb] = *(const s16x8*)&Bs[(wn * 64 + bb * 16 + l15) * 32 + l4 * 8];
#pragma unroll
    for (int a = 0; a < 4; a++)
#pragma unroll
      for (int bb = 0; bb < 4; bb++)
        acc[a][bb] = __builtin_amdgcn_mfma_f32_16x16x32_bf16(af[a], bf[bb], acc[a][bb], 0, 0, 0);
  }

#pragma unroll
  for (int bb = 0; bb < 4; bb++) {
    int col = n0 + wn * 64 + bb * 16 + l15;
    float bv = bias[col];
#pragma unroll
    for (int a = 0; a < 4; a++) {
      int row0 = m0 + wm * 64 + a * 16 + l4 * 4;
#pragma unroll
      for (int r = 0; r < 4; r++)
        out[(size_t)(row0 + r) * CC + col] = acc[a][bb][r] + bv;
    }
  }
}

// ---------------------------------------------------------------------------
// Talking-heads attention, all-MFMA, exp2-folded, conflict-free pitches.
// Block 512 thr per (b, 16 q-rows); grid (8,64) -> b pinned per XCD.
// ROUND-0 structure restored exactly (2 barriers/mt both passes, single S
// buffer, no setprio): round-2's pass-1 dbuf and/or setprio cost +31us of
// unattributed stall on this lockstep 8-wave kernel. packhl kept (verified
// -5 VALUBusy points, round 2).
// pass1: QK -> Sb (bf16 single, pitch 20), T=wl'.S+bl' (1 MFMA), l += exp2(T)
// between: ll2 = log2(l);  Tinit = bl' - ll2   (folds 1/l into C-init)
// pass2: QK -> Sb hi/lo (pitch 28), T via 2 MFMA, Pn=exp2(T) packed hi/lo in
//        regs == ww B-frag, U via 2 MFMA + bw -> Ut (pitch 36, dbuf),
//        O^T += mfma(V^T global, Ut)
// Pitches 20/28/36 u16 = 10/14/18-bank strides (gcd 2 with 32 -> free).
// ---------------------------------------------------------------------------
#define SB_BYTES 28736            // 512*28*2 + 64 tail, zero-inited
#define UT_OFF   SB_BYTES
#define UT_ELE   6912             // 192*36 u16 per buffer
#define LL2_OFF  (SB_BYTES + 27648)
#define SM_TOTAL (LL2_OFF + 1088)

__global__ __launch_bounds__(512, 4) void attn_kernel(
    const u16* __restrict__ qg, const u16* __restrict__ kg, const u16* __restrict__ vtg,
    const float* __restrict__ wlg, const float* __restrict__ blg,
    const float* __restrict__ wwg, const float* __restrict__ bwg,
    u16* __restrict__ aout) {
  __shared__ __align__(16) char smem[SM_TOTAL];
  u16* Sb = (u16*)smem;
  u16* Ut0 = (u16*)(smem + UT_OFF);
  float* lpart = (float*)(smem + UT_OFF);   // 8KB, consumed before Ut use
  float* ll2 = (float*)(smem + LL2_OFF);    // [16][17]

  const int b = blockIdx.x, i0 = blockIdx.y * 16;
  const int tid = threadIdx.x;
  const int w = tid >> 6, lane = tid & 63, l15 = lane & 15, l4 = lane >> 4;
  const float RLN2 = 1.44269504088896340736f;

  // zero Sb region once: MFMA pads must never be NaN bit patterns
  for (int j = tid; j < SB_BYTES / 4; j += 512) ((u32*)smem)[j] = 0;
  __syncthreads();  // zero visible before any S writes (r0 had a latent race)

  // ---- weight A-fragments: lane holds A[row=g=l15][k=l4*8+j] ----
  s16x8 wlS, wlA1, wlA2, wwA1, wwA2;
#pragma unroll
  for (int j = 0; j < 8; j++) {
    int k = l4 * 8 + j;
    float v1 = (k < 12 && l15 < 12) ? wlg[k * 12 + l15] * RLN2 : 0.f;
    wlS[j] = (short)f2bf(v1);
    int h = k >> 1, pt = k & 1;
    float v2 = (h < 12 && l15 < 12) ? wlg[h * 12 + l15] * RLN2 : 0.f;
    u16 h2 = f2bf(v2); u16 lo2 = f2bf(v2 - bf2f(h2));
    wlA1[j] = (short)h2; wlA2[j] = (short)(pt ? 0 : lo2);
    float v3 = (h < 12 && l15 < 12) ? wwg[h * 12 + l15] : 0.f;
    u16 h3 = f2bf(v3); u16 lo3 = f2bf(v3 - bf2f(h3));
    wwA1[j] = (short)h3; wwA2[j] = (short)(pt ? 0 : lo3);
  }
  int gr[4]; float blv[4], bwv[4];
#pragma unroll
  for (int r = 0; r < 4; r++) {
    gr[r] = l4 * 4 + r;
    blv[r] = (gr[r] < 12) ? blg[gr[r]] * RLN2 : 0.f;
    bwv[r] = (gr[r] < 12) ? bwg[gr[r]] : 0.f;
  }

  // ---- QK jobs (12h x 2mb over 8 waves) + Q B-frags ----
  int jh[3], jmb[3];
  s16x8 qf[3][2];
#pragma unroll
  for (int jt = 0; jt < 3; jt++) {
    int j = w * 3 + jt;
    jh[jt] = j % 12; jmb[jt] = j / 12;
    const u16* qp = qg + (((size_t)((b * HH + jh[jt]) * NN + i0 + l15)) << 6) + l4 * 8;
    qf[jt][0] = *(const s16x8*)qp;
    qf[jt][1] = *(const s16x8*)(qp + 32);
  }

  // ================= pass 1: sum-exp (single-bf16 S) =================
  float la[4] = {0.f, 0.f, 0.f, 0.f};
  for (int mt = 0; mt < 32; mt++) {
    const int m0 = mt * 32;
#pragma unroll
    for (int jt = 0; jt < 3; jt++) {
      f32x4 c = (f32x4){0.f, 0.f, 0.f, 0.f};
      const u16* kp = kg + (((size_t)((b * HH + jh[jt]) * NN + m0 + jmb[jt] * 16 + l15)) << 6) + l4 * 8;
      c = __builtin_amdgcn_mfma_f32_16x16x32_bf16(*(const s16x8*)kp, qf[jt][0], c, 0, 0, 0);
      c = __builtin_amdgcn_mfma_f32_16x16x32_bf16(*(const s16x8*)(kp + 32), qf[jt][1], c, 0, 0, 0);
      int cb = (jmb[jt] * 16 + l4 * 4) * 16 + l15;
#pragma unroll
      for (int r = 0; r < 4; r++)
        Sb[(size_t)(cb + r * 16) * 20 + jh[jt]] = f2bf(c[r]);
    }
    __syncthreads();
#pragma unroll
    for (int tt = 0; tt < 4; tt++) {
      int t = w * 4 + tt;
      s16x8 bS = lds_read8(Sb + (size_t)(t * 16 + l15) * 20 + l4 * 8);
      f32x4 T = (f32x4){blv[0], blv[1], blv[2], blv[3]};
      T = __builtin_amdgcn_mfma_f32_16x16x32_bf16(wlS, bS, T, 0, 0, 0);
#pragma unroll
      for (int r = 0; r < 4; r++) la[r] += hw_exp2(T[r]);
    }
    __syncthreads();
  }

  // ---- reduce l across waves; Tinit = bl' - log2(l) ----
#pragma unroll
  for (int r = 0; r < 4; r++) lpart[w * 256 + gr[r] * 16 + l15] = la[r];
  __syncthreads();
  if (tid < 256) {
    float s = 0.f;
#pragma unroll
    for (int w2 = 0; w2 < 8; w2++) s += lpart[w2 * 256 + tid];
    ll2[(tid >> 4) * 17 + (tid & 15)] = hw_log2(s);
  }
  __syncthreads();
  float Tinit[4];
#pragma unroll
  for (int r = 0; r < 4; r++) Tinit[r] = blv[r] - ll2[gr[r] * 17 + l15];

  // ================= pass 2: full (hi/lo S, in-reg P, PV) =================
  const int db = w >> 1, pvh = (w & 1) * 6;
  f32x4 O[6];
#pragma unroll
  for (int jp = 0; jp < 6; jp++) O[jp] = (f32x4){0.f, 0.f, 0.f, 0.f};

  for (int mt = 0; mt < 32; mt++) {
    const int m0 = mt * 32;
    u16* Utb = Ut0 + (mt & 1) * UT_ELE;
#pragma unroll
    for (int jt = 0; jt < 3; jt++) {
      f32x4 c = (f32x4){0.f, 0.f, 0.f, 0.f};
      const u16* kp = kg + (((size_t)((b * HH + jh[jt]) * NN + m0 + jmb[jt] * 16 + l15)) << 6) + l4 * 8;
      c = __builtin_amdgcn_mfma_f32_16x16x32_bf16(*(const s16x8*)kp, qf[jt][0], c, 0, 0, 0);
      c = __builtin_amdgcn_mfma_f32_16x16x32_bf16(*(const s16x8*)(kp + 32), qf[jt][1], c, 0, 0, 0);
      int cb = (jmb[jt] * 16 + l4 * 4) * 16 + l15;
#pragma unroll
      for (int r = 0; r < 4; r++)
        *(u32*)(Sb + (size_t)(cb + r * 16) * 28 + 2 * jh[jt]) = packhl(c[r]);
    }
    __syncthreads();
#pragma unroll
    for (int tt = 0; tt < 4; tt++) {
      int t = w * 4 + tt;
      s16x8 bS = lds_read8(Sb + (size_t)(t * 16 + l15) * 28 + l4 * 8);
      f32x4 T = (f32x4){Tinit[0], Tinit[1], Tinit[2], Tinit[3]};
      T = __builtin_amdgcn_mfma_f32_16x16x32_bf16(wlA1, bS, T, 0, 0, 0);
      T = __builtin_amdgcn_mfma_f32_16x16x32_bf16(wlA2, bS, T, 0, 0, 0);
      u32x4 pk;
#pragma unroll
      for (int r = 0; r < 4; r++) pk[r] = packhl(hw_exp2(T[r]));  // normalized via Tinit
      s16x8 bP = __builtin_bit_cast(s16x8, pk);  // == ww-mix B-frag in-lane
      f32x4 U = (f32x4){bwv[0], bwv[1], bwv[2], bwv[3]};
      U = __builtin_amdgcn_mfma_f32_16x16x32_bf16(wwA1, bP, U, 0, 0, 0);
      U = __builtin_amdgcn_mfma_f32_16x16x32_bf16(wwA2, bP, U, 0, 0, 0);
#pragma unroll
      for (int r = 0; r < 4; r++)
        if (gr[r] < 12) Utb[(size_t)(gr[r] * 16 + l15) * 36 + t] = f2bf(U[r]);
    }
    __syncthreads();
#pragma unroll
    for (int jp = 0; jp < 6; jp++) {
      const int h = pvh + jp;
      s16x8 aV = *(const s16x8*)(vtg + (((size_t)((b * HH + h) * DD + db * 16 + l15)) << 10) + m0 + l4 * 8);
      s16x8 bU = lds_read8(Utb + (size_t)(h * 16 + l15) * 36 + l4 * 8);
      O[jp] = __builtin_amdgcn_mfma_f32_16x16x32_bf16(aV, bU, O[jp], 0, 0, 0);
    }
  }

  // epilogue: O^T frag rows=d, col=i -> ao[b][n][h*64+d]
#pragma unroll
  for (int jp = 0; jp < 6; jp++) {
    const int h = pvh + jp;
    const int d0 = db * 16 + l4 * 4;
    s16x4 pk4;
#pragma unroll
    for (int r = 0; r < 4; r++) pk4[r] = (short)f2bf(O[jp][r]);
    *(s16x4*)(aout + ((size_t)(b * NN) + i0 + l15) * CC + h * DD + d0) = pk4;
  }
}

extern "C" void kernel_launch(void* const* d_in, const int* in_sizes, int n_in,
                              void* d_out, int out_size, void* d_ws, size_t ws_size,
                              hipStream_t stream) {
  const float* x      = (const float*)d_in[0];
  const float* w_qkv  = (const float*)d_in[1];
  const float* b_qkv  = (const float*)d_in[2];
  const float* w_l    = (const float*)d_in[3];
  const float* b_l    = (const float*)d_in[4];
  const float* w_w    = (const float*)d_in[5];
  const float* b_w    = (const float*)d_in[6];
  const float* w_proj = (const float*)d_in[7];
  const float* b_proj = (const float*)d_in[8];

  const size_t per = (size_t)BB * HH * NN * DD;  // 6,291,456
  u16* xb  = (u16*)d_ws;
  u16* wqt = xb + per;
  u16* wpt = wqt + (size_t)3 * CC * CC;
  u16* q   = wpt + (size_t)CC * CC;
  u16* k   = q + per;
  u16* vt  = k + per;
  u16* ao  = vt + per;

  convx_kernel<<<3072, 256, 0, stream>>>(x, xb);
  transpose_kernel<<<dim3(3 * CC / 32, CC / 32), 256, 0, stream>>>(w_qkv, wqt, CC, 3 * CC);
  transpose_kernel<<<dim3(CC / 32, CC / 32), 256, 0, stream>>>(w_proj, wpt, CC, CC);
  qkv_gemm<<<dim3(64, 18), 256, 0, stream>>>(xb, wqt, b_qkv, q, k, vt);
  attn_kernel<<<dim3(BB, NN / 16), 512, 0, stream>>>(q, k, vt, w_l, b_l, w_w, b_w, ao);
  proj_gemm<<<dim3(64, 6), 256, 0, stream>>>(ao, wpt, b_proj, (float*)d_out);
}